// Round 7
// baseline (687.656 us; speedup 1.0000x reference)
//
#include <hip/hip_runtime.h>
#include <hip/hip_bf16.h>
#include <math.h>
#include <stdint.h>

#define N_ROWS 8192
#define DIM 512
#define INV_TAU 5.0f
#define EXP5 148.41315910257660342f   // exp(1/tau) = exp(5)

typedef float f32x4 __attribute__((ext_vector_type(4)));
typedef int   i32x4 __attribute__((ext_vector_type(4)));
typedef int   i32x8 __attribute__((ext_vector_type(8)));

union Frag8 {            // one K=128 fragment: 32 B/lane = 8 VGPRs
  i32x8 v8;
  struct { i32x4 lo, hi; } s;
};

__device__ __forceinline__ void gload_lds16(const void* g, void* l) {
  __builtin_amdgcn_global_load_lds(
      (__attribute__((address_space(1))) void*)(void*)g,
      (__attribute__((address_space(3))) void*)l,
      16, 0, 0);
}

// Block = 16 rows (one MFMA group), 256 threads. Thread t: row t>>4, k-span
// (t&15)*32..+31. Norms via 16-lane butterfly, fp32 diag dot, fp8 e4m3
// quantization into the K=128 MX-fragment packed layout:
//   unit (g=row/16, ks=k/128) = 2048 B, two lane-major halves:
//     h=0 @ +0   : lane l's bytes k=(l>>4)*32+ 0..15 (v[0:3])
//     h=1 @ +1024: lane l's bytes k=(l>>4)*32+16..31 (v[4:7])
//   lane l: row l&15. 8 KB per group per array. One frag = 2 int4 loads.
// Scatter goes through LDS so global writes are coalesced int4.
// Also zeroes r1/r2/brow/bcol/out.
__global__ __launch_bounds__(256) void normalize_kernel(
    const float* __restrict__ z1, const float* __restrict__ z2,
    uint8_t* __restrict__ h1p, uint8_t* __restrict__ h2p,
    float* __restrict__ dvec,
    float* __restrict__ r1, float* __restrict__ r2,
    float* __restrict__ brow, float* __restrict__ bcol,
    float* __restrict__ out) {
  __shared__ __align__(16) uint8_t L[16384];  // 8KB h1-part, 8KB h2-part
  const int t = threadIdx.x;
  const int lr = t >> 4;          // row in group 0..15
  const int kb = t & 15;          // this thread's 32-elem k-block
  const int row = blockIdx.x * 16 + lr;
  const float4* p1 = (const float4*)(z1 + (size_t)row * DIM + kb * 32);
  const float4* p2 = (const float4*)(z2 + (size_t)row * DIM + kb * 32);
  float4 a[8], b[8];
  float s1 = 0.f, s2 = 0.f, s3 = 0.f;
#pragma unroll
  for (int i = 0; i < 8; i++) {
    a[i] = p1[i]; b[i] = p2[i];
    s1 += a[i].x*a[i].x + a[i].y*a[i].y + a[i].z*a[i].z + a[i].w*a[i].w;
    s2 += b[i].x*b[i].x + b[i].y*b[i].y + b[i].z*b[i].z + b[i].w*b[i].w;
    s3 += a[i].x*b[i].x + a[i].y*b[i].y + a[i].z*b[i].z + a[i].w*b[i].w;
  }
  for (int m = 1; m <= 8; m <<= 1) {
    s1 += __shfl_xor(s1, m);
    s2 += __shfl_xor(s2, m);
    s3 += __shfl_xor(s3, m);
  }
  const float inv1 = 1.0f / fmaxf(sqrtf(s1), 1e-12f);
  const float inv2 = 1.0f / fmaxf(sqrtf(s2), 1e-12f);
  int w1[8], w2[8];
#pragma unroll
  for (int i = 0; i < 8; i++) {
    int w = __builtin_amdgcn_cvt_pk_fp8_f32(a[i].x*inv1, a[i].y*inv1, 0, false);
    w1[i] = __builtin_amdgcn_cvt_pk_fp8_f32(a[i].z*inv1, a[i].w*inv1, w, true);
    w = __builtin_amdgcn_cvt_pk_fp8_f32(b[i].x*inv2, b[i].y*inv2, 0, false);
    w2[i] = __builtin_amdgcn_cvt_pk_fp8_f32(b[i].z*inv2, b[i].w*inv2, w, true);
  }
  // K=128 packed LDS scatter: this k-block is unit ks=kb>>2, lane
  // l=(kb&3)*16+lr; first 16B -> h=0, last 16B -> h=1.
  const int ks = kb >> 2;
  const int l = (kb & 3) * 16 + lr;
  *(int4*)(L + ks * 2048 + l * 16)          = make_int4(w1[0], w1[1], w1[2], w1[3]);
  *(int4*)(L + ks * 2048 + 1024 + l * 16)   = make_int4(w1[4], w1[5], w1[6], w1[7]);
  *(int4*)(L + 8192 + ks * 2048 + l * 16)        = make_int4(w2[0], w2[1], w2[2], w2[3]);
  *(int4*)(L + 8192 + ks * 2048 + 1024 + l * 16) = make_int4(w2[4], w2[5], w2[6], w2[7]);
  if (kb == 0) dvec[row] = s3 * inv1 * inv2;
  if (t < 16) {
    const int i = blockIdx.x * 16 + t;
    r1[i] = 0.f; r2[i] = 0.f; brow[i] = 0.f; bcol[i] = 0.f;
    if (i == 0) out[0] = 0.f;
  }
  __syncthreads();
  const size_t gb = (size_t)blockIdx.x * 8192;
  int4* g1 = (int4*)(h1p + gb);
  int4* g2 = (int4*)(h2p + gb);
  const int4* Lv = (const int4*)L;
  g1[t]       = Lv[t];
  g1[t + 256] = Lv[t + 256];
  g2[t]       = Lv[t + 512];
  g2[t + 256] = Lv[t + 768];
}

// Upper triangle of W W^T, W=[h1;h2] = 128 row-blocks of 128 (flat 8 MiB).
// ROW-STRIP blocks: block (bi, jg) computes tiles (bi, bj0..bj0+L-1),
// bj0 = bi+4*jg, L = min(4, 128-bj0). Grid 128x32; bj0>127 -> ghost exit.
//
// Round-5/6 post-mortem: persistent Af (64 regs) live across the in-loop
// epilogue spilled at BOTH (256,3) and (256,2) — with acc in AGPRs the
// unified-file arch half (~128) must hold Af+B+addr+exp-temps (~150).
// THIS round: NO persistent Af. Each chunk's A fragments (16 regs) are
// prefetched from global one phase ahead, double-buffered (Aa/Ab, 32
// transient regs) — A panel is L2/L1-hot (64 KB, re-read 4x/block, +0 HBM).
// Ledger: each phase issues A(k+1)[4] THEN S(k+2)[4] (sched_barrier-pinned
// order); phase-top vmcnt(4) leaves exactly the newest stage in flight and
// guarantees A(k)+S(k) retired (in-order). vmcnt(0) only at the last phase.
// Epilogue exp loops carry sched_barrier(0) per fn-group to cap temp
// liveness (rounds-5/6 showed the scheduler otherwise batches 64 exps).
__global__ __launch_bounds__(256, 3) void expsum_kernel(
    const uint8_t* __restrict__ Wp,
    float* __restrict__ r1, float* __restrict__ r2,
    float* __restrict__ brow, float* __restrict__ bcol) {
  __shared__ __align__(16) uint8_t Bs[49152];   // 3 x 16 KB chunk buffers
  __shared__ __align__(16) float Red[256];      // [0,128) rows, [128,256) cols

  const int bi  = blockIdx.x;                 // 0..127
  const int bj0 = bi + 4 * (int)blockIdx.y;
  if (bj0 > 127) return;                      // ghost (block-uniform)
  const int L = (128 - bj0 < 4) ? (128 - bj0) : 4;

  const int t = threadIdx.x;
  const int w = t >> 6;         // wave 0..3: rows 32w..32w+31
  const int lane = t & 63;
  const int l16 = lane & 15;
  const int kq = lane >> 4;     // 0..3
  const int iOutBase = (bi & 63) * 128;

  const uint8_t* Bg0 = Wp + (size_t)bj0 * 65536;
  const uint8_t* Ag  = Wp + (size_t)(bi * 8 + w * 2) * 8192 + (size_t)lane * 16;

  // A fragments for one chunk ks: rows 32w..32w+31 = units (w*2, w*2+1).
#define A_LOAD(KS, A0, A1)                                                  \
  do {                                                                      \
    A0.s.lo = *(const i32x4*)(Ag + (KS)*2048);                              \
    A0.s.hi = *(const i32x4*)(Ag + (KS)*2048 + 1024);                       \
    A1.s.lo = *(const i32x4*)(Ag + 8192 + (KS)*2048);                       \
    A1.s.hi = *(const i32x4*)(Ag + 8192 + (KS)*2048 + 1024);                \
  } while (0)

  // Chunk ks (16 KB) of tile base BGT: frag fn's unit at fn*8192 + ks*2048.
  // LDS dest is wave-uniform base + lane*16 (cb = (r*256+t)*16).
#define STAGE(BGT, KS, BUFOFS)                                              \
  do {                                                                      \
    _Pragma("unroll") for (int r_ = 0; r_ < 4; r_++) {                      \
      const int cb_ = (r_ * 256 + t) * 16;                                  \
      gload_lds16((BGT) + ((cb_ >> 11) << 13) + (KS)*2048 + (cb_ & 2047),   \
                  Bs + (BUFOFS) + cb_);                                     \
    }                                                                       \
  } while (0)

  // Single-B consumption (8 live B-VGPRs); A from the named double-buffer.
#define COMPUTE_CHUNK(A0, A1, BUFOFS)                                       \
  do {                                                                      \
    const uint8_t* Bc_ = (const uint8_t*)Bs + (BUFOFS) + lane * 16;         \
    _Pragma("unroll") for (int fn_ = 0; fn_ < 8; fn_++) {                   \
      Frag8 B0_;                                                            \
      B0_.s.lo = *(const i32x4*)(Bc_ + fn_ * 2048);                         \
      B0_.s.hi = *(const i32x4*)(Bc_ + fn_ * 2048 + 1024);                  \
      acc[0][fn_] = __builtin_amdgcn_mfma_scale_f32_16x16x128_f8f6f4(       \
          A0.v8, B0_.v8, acc[0][fn_], 0, 0, 0, 0x7F7F7F7F, 0, 0x7F7F7F7F);  \
      acc[1][fn_] = __builtin_amdgcn_mfma_scale_f32_16x16x128_f8f6f4(       \
          A1.v8, B0_.v8, acc[1][fn_], 0, 0, 0, 0x7F7F7F7F, 0, 0x7F7F7F7F);  \
    }                                                                       \
  } while (0)

#define VMW4 asm volatile("s_waitcnt vmcnt(4)" ::: "memory")
#define VMW0 asm volatile("s_waitcnt vmcnt(0)" ::: "memory")
#define LGK0 asm volatile("s_waitcnt lgkmcnt(0)" ::: "memory")
#define BAR  __builtin_amdgcn_s_barrier()
#define SCH  __builtin_amdgcn_sched_barrier(0)

  Frag8 Aa0, Aa1, Ab0, Ab1;   // A double-buffer: even chunks Aa, odd Ab

  // ---- prologue (ledger order: A(0), S(c0), S(c1)) ----
  A_LOAD(0, Aa0, Aa1);
  SCH;
  STAGE(Bg0, 0, 0);
  STAGE(Bg0, 1, 16384);
  SCH;

  f32x4 acc[2][8];
#pragma unroll
  for (int a = 0; a < 2; a++)
#pragma unroll
    for (int b = 0; b < 8; b++)
#pragma unroll
      for (int r = 0; r < 4; r++) acc[a][b][r] = 0.0f;

  float rowp[2][4];
#pragma unroll
  for (int fm = 0; fm < 2; fm++)
#pragma unroll
    for (int r = 0; r < 4; r++) rowp[fm][r] = 0.0f;

  int b0 = 0, b1 = 16384, b2 = 32768;   // rotating buffer byte offsets
#define ROT { const int n0_ = b1, n1_ = b2, n2_ = b0; b0 = n0_; b1 = n1_; b2 = n2_; }

  for (int tt = 0; tt < L; ++tt) {
    const int bj = bj0 + tt;
    const bool haveNext = (tt + 1 < L);
    const uint8_t* Bg  = Bg0 + (size_t)tt * 65536;
    const uint8_t* Bgn = Bg + 65536;

    // q=0: compute c(4t+0) [Aa, b0]; issue A(1)->Ab, S(c2)->b2
    VMW4; BAR; SCH;
    A_LOAD(1, Ab0, Ab1);
    SCH;
    STAGE(Bg, 2, b2);
    SCH;
    __builtin_amdgcn_s_setprio(1);
    COMPUTE_CHUNK(Aa0, Aa1, b0);
    __builtin_amdgcn_s_setprio(0);
    ROT;

    // q=1: compute c1 [Ab]; issue A(2)->Aa, S(c3)
    VMW4; BAR; SCH;
    A_LOAD(2, Aa0, Aa1);
    SCH;
    STAGE(Bg, 3, b2);
    SCH;
    __builtin_amdgcn_s_setprio(1);
    COMPUTE_CHUNK(Ab0, Ab1, b0);
    __builtin_amdgcn_s_setprio(0);
    ROT;

    // q=2: compute c2 [Aa]; issue A(3)->Ab, S(next tile c0)
    VMW4; BAR; SCH;
    A_LOAD(3, Ab0, Ab1);
    SCH;
    if (haveNext) STAGE(Bgn, 0, b2);
    SCH;
    __builtin_amdgcn_s_setprio(1);
    COMPUTE_CHUNK(Aa0, Aa1, b0);
    __builtin_amdgcn_s_setprio(0);
    ROT;

    // q=3: compute c3 [Ab]; issue A(next ks0)->Aa, S(next c1)
    if (haveNext) { VMW4; } else { VMW0; }
    BAR; SCH;
    if (haveNext) A_LOAD(0, Aa0, Aa1);
    SCH;
    if (haveNext) STAGE(Bgn, 1, b2);
    SCH;
    __builtin_amdgcn_s_setprio(1);
    COMPUTE_CHUNK(Ab0, Ab1, b0);
    __builtin_amdgcn_s_setprio(0);
    ROT;

    // ---- per-tile epilogue (overlaps next tile's in-flight loads) ----
    // C/D layout (shape-determined): col=lane&15, row=kq*4+reg.
    const bool diagb = (bj == bi);
    const bool flushR = (!haveNext) || (bi < 64 && bj == 63);
    float* rowsOut = (bi < 64) ? ((bj < 64) ? r1 : brow) : r2;
    float* colsOut = (bj < 64) ? r1 : ((bi < 64) ? bcol : r2);
    const int jOutBase = (bj & 63) * 128;

    float colp[8];
#pragma unroll
    for (int fn = 0; fn < 8; fn++) colp[fn] = 0.0f;

    if (!diagb) {
#pragma unroll
      for (int fn = 0; fn < 8; fn++) {
#pragma unroll
        for (int fm = 0; fm < 2; fm++)
#pragma unroll
          for (int r = 0; r < 4; r++) {
            const float e = __expf(acc[fm][fn][r] * INV_TAU);
            rowp[fm][r] += e;
            colp[fn] += e;
          }
        SCH;   // cap exp-temp liveness (anti-spill; rounds 5/6 lesson)
      }
    } else {
      // within-tile (i0==j0): rows keep ti<=tj, cols keep ti<tj
#pragma unroll
      for (int fn = 0; fn < 8; fn++) {
#pragma unroll
        for (int fm = 0; fm < 2; fm++)
#pragma unroll
          for (int r = 0; r < 4; r++) {
            const int ti = w * 32 + fm * 16 + kq * 4 + r;
            const int tj = fn * 16 + l16;
            const float e = __expf(acc[fm][fn][r] * INV_TAU);
            rowp[fm][r] += (ti <= tj) ? e : 0.0f;
            colp[fn] += (ti < tj) ? e : 0.0f;
          }
        SCH;
      }
    }
    // reset acc for next tile
#pragma unroll
    for (int fm = 0; fm < 2; fm++)
#pragma unroll
      for (int fn = 0; fn < 8; fn++)
#pragma unroll
        for (int r = 0; r < 4; r++) acc[fm][fn][r] = 0.0f;

    // Raw-barrier reduction (NO __syncthreads: it would drain the in-flight
    // next-tile loads to vmcnt(0)). lgkmcnt(0) makes LDS writes visible.
    if (t < 128) Red[128 + t] = 0.0f;
    LGK0; BAR; SCH;
    // col partials: reduce over kq groups, LDS-atomic across waves
#pragma unroll
    for (int fn = 0; fn < 8; fn++) {
      float v = colp[fn];
      v += __shfl_xor(v, 16);
      v += __shfl_xor(v, 32);
      if (kq == 0) atomicAdd(&Red[128 + fn * 16 + l16], v);
    }
    if (flushR) {
      // row sums: reduce across the 16 lanes sharing kq; unique dest
#pragma unroll
      for (int fm = 0; fm < 2; fm++)
#pragma unroll
        for (int r = 0; r < 4; r++) {
          float v = rowp[fm][r];
          v += __shfl_xor(v, 1);
          v += __shfl_xor(v, 2);
          v += __shfl_xor(v, 4);
          v += __shfl_xor(v, 8);
          if (l16 == 0) Red[w * 32 + fm * 16 + kq * 4 + r] = v;
        }
    }
    LGK0; BAR; SCH;
    if (t < 128) {
      if (flushR) atomicAdd(&rowsOut[iOutBase + t], Red[t]);
    } else {
      atomicAdd(&colsOut[jOutBase + (t - 128)], Red[t]);
    }
    if (flushR) {
#pragma unroll
      for (int fm = 0; fm < 2; fm++)
#pragma unroll
        for (int r = 0; r < 4; r++) rowp[fm][r] = 0.0f;
    }
  }

#undef A_LOAD
#undef STAGE
#undef COMPUTE_CHUNK
#undef VMW4
#undef VMW0
#undef LGK0
#undef BAR
#undef SCH
#undef ROT
}

__global__ __launch_bounds__(256) void finalize_kernel(
    const float* __restrict__ r1, const float* __restrict__ r2,
    const float* __restrict__ brow, const float* __restrict__ bcol,
    const float* __restrict__ dvec, float* __restrict__ out) {
  const int i = blockIdx.x * 256 + threadIdx.x;
  const float den1 = r1[i] + brow[i] - EXP5;
  const float den2 = r2[i] + bcol[i] - EXP5;
  float v = 0.5f * (logf(den1) + logf(den2)) - INV_TAU * dvec[i];
  for (int m = 32; m; m >>= 1) v += __shfl_xor(v, m);
  __shared__ float red[4];
  const int wave = threadIdx.x >> 6;
  if ((threadIdx.x & 63) == 0) red[wave] = v;
  __syncthreads();
  if (threadIdx.x == 0) atomicAdd(out, red[0] + red[1] + red[2] + red[3]);
}

extern "C" void kernel_launch(void* const* d_in, const int* in_sizes, int n_in,
                              void* d_out, int out_size, void* d_ws, size_t ws_size,
                              hipStream_t stream) {
  const float* z1 = (const float*)d_in[0];
  const float* z2 = (const float*)d_in[1];
  float* out = (float*)d_out;

  char* ws = (char*)d_ws;
  uint8_t* h1p = (uint8_t*)ws;                 // 4 MiB fp8 K128-packed
  uint8_t* h2p = (uint8_t*)(ws + (4u << 20));  // 4 MiB, contiguous -> W flat
  float* r1   = (float*)(ws + (8u << 20));
  float* r2   = r1 + N_ROWS;
  float* brow = r2 + N_ROWS;
  float* bcol = brow + N_ROWS;
  float* dvec = bcol + N_ROWS;

  normalize_kernel<<<N_ROWS / 16, 256, 0, stream>>>(
      z1, z2, h1p, h2p, dvec, r1, r2, brow, bcol, out);
  expsum_kernel<<<dim3(128, 32), 256, 0, stream>>>(h1p, r1, r2, brow, bcol);
  finalize_kernel<<<N_ROWS / 256, 256, 0, stream>>>(r1, r2, brow, bcol, dvec, out);
}